// Round 1
// baseline (385.239 us; speedup 1.0000x reference)
//
#include <hip/hip_runtime.h>

// ---------------------------------------------------------------------------
// RefineIUGraphLayer: D=256, H=16, HD=16, N=16384, B=64, S=128, M=8192
// Pipeline:
//   1) qkv = seq_feat @ in_proj_w^T + in_proj_b            (bf16 MFMA gemm)
//   2) attn = MHA(qkv)                                     (f32 per-thread)
//   3) seq = attn @ out_proj_w^T + out_proj_b              (bf16 MFMA gemm)
//   4) agg = p1norm(user @ seq^T) @ seq / M                (fused flash-style)
//   5) out = user + agg @ trans_w^T + trans_b              (bf16 MFMA gemm)
// ---------------------------------------------------------------------------

typedef __bf16 bf16_t;
typedef __bf16 bf16x8 __attribute__((ext_vector_type(8)));
typedef __bf16 bf16x4 __attribute__((ext_vector_type(4)));
typedef float  f32x4  __attribute__((ext_vector_type(4)));
typedef unsigned int u32x4 __attribute__((ext_vector_type(4)));

#define MFMA16(a, b, c) __builtin_amdgcn_mfma_f32_16x16x32_bf16((a), (b), (c), 0, 0, 0)

// XOR swizzle: spreads rows 0..7 across distinct 16B LDS slots (kills the
// 16-way same-bank conflict of stride-512B / stride-128B row-major tiles).
// Applied identically on write and read (involution on 8-elem blocks).
__device__ __forceinline__ int swz256(int row, int k) { return row * 256 + (k ^ ((row & 7) << 3)); }
__device__ __forceinline__ int swz64 (int row, int k) { return row * 64  + (k ^ ((row & 7) << 3)); }

// --------------------------- f32 -> bf16 convert ---------------------------
__global__ void k_cvt(const float* __restrict__ s, bf16_t* __restrict__ d, int n4) {
    int i  = blockIdx.x * blockDim.x + threadIdx.x;
    int st = gridDim.x * blockDim.x;
    for (; i < n4; i += st) {
        float4 v = ((const float4*)s)[i];
        bf16x4 o = { (bf16_t)v.x, (bf16_t)v.y, (bf16_t)v.z, (bf16_t)v.w };
        ((bf16x4*)d)[i] = o;
    }
}

// --------- seq f32 [8192,256] -> bf16 row-major + bf16 transposed ----------
__global__ void k_cvt_seq(const float* __restrict__ seq, bf16_t* __restrict__ sb,
                          bf16_t* __restrict__ sTb) {
    __shared__ bf16_t t[64][65];
    const int c0 = blockIdx.x * 64;   // d base
    const int r0 = blockIdx.y * 64;   // j base
    const int tid = threadIdx.x;
#pragma unroll
    for (int i = 0; i < 16; ++i) {
        int e = i * 256 + tid;
        int lr = e >> 6, lc = e & 63;
        float v = seq[(size_t)(r0 + lr) * 256 + c0 + lc];
        bf16_t b = (bf16_t)v;
        sb[(size_t)(r0 + lr) * 256 + c0 + lc] = b;
        t[lc][lr] = b;
    }
    __syncthreads();
#pragma unroll
    for (int i = 0; i < 16; ++i) {
        int e = i * 256 + tid;
        int lr = e >> 6, lc = e & 63;
        sTb[(size_t)(c0 + lr) * 8192 + r0 + lc] = t[lr][lc];
    }
}

// ------------------- generic C = A @ B^T + bias (+resid) -------------------
// A [M,256] bf16, B [N,256] bf16, C [M,N] f32. Tile 64x64, 4 waves, K=256.
__global__ __launch_bounds__(256, 1)
void k_gemm_bt(const bf16_t* __restrict__ A, const bf16_t* __restrict__ B,
               const float* __restrict__ bias, const float* __restrict__ resid,
               float* __restrict__ C, int N) {
    __shared__ bf16_t Al[64 * 256];
    __shared__ bf16_t Bl[64 * 256];
    const int tid  = threadIdx.x;
    const int lane = tid & 63;
    const int w    = tid >> 6;
    const int l15  = lane & 15;
    const int l4   = lane >> 4;
    const int rb = blockIdx.y * 64, cb = blockIdx.x * 64;

    {   // stage A,B tiles (2048 16B-chunks each; 8 per thread), swizzled
        const u32x4* sa = (const u32x4*)(A + (size_t)rb * 256);
        const u32x4* sb = (const u32x4*)(B + (size_t)cb * 256);
        u32x4* da = (u32x4*)Al;
        u32x4* db = (u32x4*)Bl;
#pragma unroll
        for (int i = 0; i < 8; ++i) {
            int ch  = i * 256 + tid;
            int row = ch >> 5, cp = ch & 31;
            int sch = (ch & ~31) | (cp ^ (row & 7));
            da[sch] = sa[ch];
            db[sch] = sb[ch];
        }
    }
    __syncthreads();

    f32x4 acc[4];
#pragma unroll
    for (int n = 0; n < 4; ++n) acc[n] = (f32x4){0.f, 0.f, 0.f, 0.f};

#pragma unroll
    for (int t = 0; t < 8; ++t) {
        int k = t * 32 + l4 * 8;
        bf16x8 af = *(const bf16x8*)(Al + swz256(16 * w + l15, k));
#pragma unroll
        for (int n = 0; n < 4; ++n) {
            bf16x8 bfr = *(const bf16x8*)(Bl + swz256(16 * n + l15, k));
            acc[n] = MFMA16(af, bfr, acc[n]);
        }
    }

#pragma unroll
    for (int n = 0; n < 4; ++n) {
        int col = cb + 16 * n + l15;
        float bv = bias ? bias[col] : 0.f;
#pragma unroll
        for (int r = 0; r < 4; ++r) {
            int row = rb + 16 * w + l4 * 4 + r;
            size_t idx = (size_t)row * N + col;
            float v = acc[n][r] + bv;
            if (resid) v += resid[idx];
            C[idx] = v;
        }
    }
}

// ------------------------------- MHA (f32) ---------------------------------
// grid = B*H = 1024 blocks, 128 threads; thread t = query row t of the block's
// (b,h). qkv [8192,768]: q at col h*16, k at 256+h*16, v at 512+h*16.
__global__ __launch_bounds__(128, 1)
void k_mha(const float* __restrict__ qkv, bf16_t* __restrict__ attn) {
    __shared__ float Kl[128][17];
    __shared__ float Vl[128][17];
    const int bh = blockIdx.x;
    const int b = bh >> 4, h = bh & 15;
    const int t = threadIdx.x;
    const size_t rowbase = (size_t)b * 128;

    const float* qrow = qkv + (rowbase + t) * 768 + h * 16;
    const float* krow = qkv + (rowbase + t) * 768 + 256 + h * 16;
    const float* vrow = qkv + (rowbase + t) * 768 + 512 + h * 16;
    float q[16];
#pragma unroll
    for (int d = 0; d < 16; ++d) q[d] = qrow[d];
#pragma unroll
    for (int d = 0; d < 16; ++d) { Kl[t][d] = krow[d]; Vl[t][d] = vrow[d]; }
    __syncthreads();

    float m = -1e30f;
    for (int j = 0; j < 128; ++j) {
        float s = 0.f;
#pragma unroll
        for (int d = 0; d < 16; ++d) s += q[d] * Kl[j][d];
        m = fmaxf(m, s * 0.25f);
    }
    float sum = 0.f;
    float o[16];
#pragma unroll
    for (int d = 0; d < 16; ++d) o[d] = 0.f;
    for (int j = 0; j < 128; ++j) {
        float s = 0.f;
#pragma unroll
        for (int d = 0; d < 16; ++d) s += q[d] * Kl[j][d];
        float e = __expf(s * 0.25f - m);
        sum += e;
#pragma unroll
        for (int d = 0; d < 16; ++d) o[d] += e * Vl[j][d];
    }
    float inv = 1.f / sum;
    bf16_t* out = attn + (rowbase + t) * 256 + h * 16;
#pragma unroll
    for (int d = 0; d < 16; ++d) out[d] = (bf16_t)(o[d] * inv);
}

// ------------------- fused user-attention (the hot loop) -------------------
// agg[i] = (sum_j a_ij * seq_j) / (max(sum_j |a_ij|, 1e-12) * 8192),
// a_ij = user_i . seq_j.   BQ=64 per block, BK=64 key tiles, 8 waves (2x4).
__global__ __launch_bounds__(512, 1)
void k_user_attn(const bf16_t* __restrict__ U, const bf16_t* __restrict__ Sq,
                 const bf16_t* __restrict__ SqT, bf16_t* __restrict__ aggb) {
    __shared__ bf16_t Ul[64 * 256];   // user tile   [64 q][256 d]
    __shared__ bf16_t Kl[64 * 256];   // seq tile    [64 j][256 d]
    __shared__ bf16_t Tl[256 * 64];   // seqT tile   [256 d][64 j]
    __shared__ bf16_t Pl[64 * 64];    // scores tile [64 q][64 j] (bf16)
    __shared__ float  rs[64];

    const int tid  = threadIdx.x;
    const int lane = tid & 63;
    const int wid  = tid >> 6;     // 0..7
    const int wr   = wid >> 1;     // 0..3 : q-row strip (16 rows)
    const int wc   = wid & 1;      // 0..1 : col split
    const int l15  = lane & 15;
    const int l4   = lane >> 4;
    const int q0   = blockIdx.x * 64;

    {   // stage U tile once (2048 chunks / 512 thr = 4), swizzled
        const u32x4* su = (const u32x4*)(U + (size_t)q0 * 256);
        u32x4* du = (u32x4*)Ul;
#pragma unroll
        for (int i = 0; i < 4; ++i) {
            int ch = i * 512 + tid;
            int row = ch >> 5, cp = ch & 31;
            du[(ch & ~31) | (cp ^ (row & 7))] = su[ch];
        }
    }
    if (tid < 64) rs[tid] = 0.f;

    f32x4 oacc[8];
#pragma unroll
    for (int n = 0; n < 8; ++n) oacc[n] = (f32x4){0.f, 0.f, 0.f, 0.f};
    float rsacc[4] = {0.f, 0.f, 0.f, 0.f};

    __syncthreads();

    for (int j0 = 0; j0 < 8192; j0 += 64) {
        // ---- load next Seq / SeqT tiles into registers (global) ----
        u32x4 sreg[4], treg[4];
        {
            const u32x4* src = (const u32x4*)(Sq + (size_t)j0 * 256);
#pragma unroll
            for (int i = 0; i < 4; ++i) sreg[i] = src[i * 512 + tid];
#pragma unroll
            for (int i = 0; i < 4; ++i) {
                int ch = i * 512 + tid;       // 0..2047
                int dr = ch >> 3;             // d row (0..255)
                int cp = ch & 7;              // 16B chunk in 64-col row
                treg[i] = *(const u32x4*)(SqT + (size_t)dr * 8192 + j0 + cp * 8);
            }
        }
        __syncthreads();   // prev iteration's PV reads complete
        {   // ---- write tiles to LDS, swizzled ----
            u32x4* dk = (u32x4*)Kl;
            u32x4* dt = (u32x4*)Tl;
#pragma unroll
            for (int i = 0; i < 4; ++i) {
                int ch = i * 512 + tid;
                int row = ch >> 5, cp = ch & 31;
                dk[(ch & ~31) | (cp ^ (row & 7))] = sreg[i];
            }
#pragma unroll
            for (int i = 0; i < 4; ++i) {
                int ch = i * 512 + tid;
                int row = ch >> 3, cp = ch & 7;
                dt[(ch & ~7) | (cp ^ (row & 7))] = treg[i];
            }
        }
        __syncthreads();   // tiles visible

        // ---- S-GEMM: S[64x64] = U_tile @ Seq_tile^T (K=256) ----
        f32x4 sacc[2];
        sacc[0] = (f32x4){0.f, 0.f, 0.f, 0.f};
        sacc[1] = (f32x4){0.f, 0.f, 0.f, 0.f};
#pragma unroll
        for (int t = 0; t < 8; ++t) {
            int k = t * 32 + l4 * 8;
            bf16x8 af = *(const bf16x8*)(Ul + swz256(16 * wr + l15, k));
#pragma unroll
            for (int c = 0; c < 2; ++c) {
                bf16x8 bfr = *(const bf16x8*)(Kl + swz256(32 * wc + 16 * c + l15, k));
                sacc[c] = MFMA16(af, bfr, sacc[c]);
            }
        }
        // ---- row |.| partial sums + P -> bf16 LDS ----
#pragma unroll
        for (int c = 0; c < 2; ++c) {
#pragma unroll
            for (int r = 0; r < 4; ++r) {
                float v = sacc[c][r];
                rsacc[r] += fabsf(v);
                int prow = 16 * wr + l4 * 4 + r;
                int pcol = 32 * wc + 16 * c + l15;
                Pl[swz64(prow, pcol)] = (bf16_t)v;
            }
        }
        __syncthreads();   // P visible

        // ---- PV: O[64x256] += P[64x64] @ SeqT_tile^T (K=64) ----
#pragma unroll
        for (int t = 0; t < 2; ++t) {
            int k = t * 32 + l4 * 8;
            bf16x8 af = *(const bf16x8*)(Pl + swz64(16 * wr + l15, k));
#pragma unroll
            for (int n = 0; n < 8; ++n) {
                bf16x8 bfr = *(const bf16x8*)(Tl + swz64(128 * wc + 16 * n + l15, k));
                oacc[n] = MFMA16(af, bfr, oacc[n]);
            }
        }
    }

    // ---- reduce row-sums: 16-lane butterfly, then 2 adds per row ----
#pragma unroll
    for (int r = 0; r < 4; ++r) {
        float v = rsacc[r];
        v += __shfl_xor(v, 1, 16);
        v += __shfl_xor(v, 2, 16);
        v += __shfl_xor(v, 4, 16);
        v += __shfl_xor(v, 8, 16);
        if (l15 == 0) atomicAdd(&rs[16 * wr + l4 * 4 + r], v);
    }
    __syncthreads();

    // ---- epilogue: scale by 1/(max(rowsum,1e-12)*M), write bf16 ----
#pragma unroll
    for (int r = 0; r < 4; ++r) {
        int row = 16 * wr + l4 * 4 + r;
        float scale = 1.f / (fmaxf(rs[row], 1e-12f) * 8192.f);
#pragma unroll
        for (int n = 0; n < 8; ++n) {
            int d = 128 * wc + 16 * n + l15;
            aggb[(size_t)(q0 + row) * 256 + d] = (bf16_t)(oacc[n][r] * scale);
        }
    }
}

// ---------------------------------------------------------------------------
extern "C" void kernel_launch(void* const* d_in, const int* in_sizes, int n_in,
                              void* d_out, int out_size, void* d_ws, size_t ws_size,
                              hipStream_t stream) {
    const float* user_feat  = (const float*)d_in[0];   // [16384,256]
    const float* seq_feat   = (const float*)d_in[1];   // [64,128,256]
    const float* in_proj_w  = (const float*)d_in[2];   // [768,256]
    const float* in_proj_b  = (const float*)d_in[3];   // [768]
    const float* out_proj_w = (const float*)d_in[4];   // [256,256]
    const float* out_proj_b = (const float*)d_in[5];   // [256]
    const float* trans_w    = (const float*)d_in[6];   // [256,256]
    const float* trans_b    = (const float*)d_in[7];   // [256]
    float* out = (float*)d_out;                        // [16384,256]

    // workspace carve-up (all 256B aligned)
    char* w = (char*)d_ws;
    size_t off = 0;
    auto take = [&](size_t bytes) { void* p = w + off; off += (bytes + 255) & ~(size_t)255; return p; };
    bf16_t* Ub    = (bf16_t*)take((size_t)16384 * 256 * 2);
    bf16_t* Xb    = (bf16_t*)take((size_t)8192 * 256 * 2);
    bf16_t* W1b   = (bf16_t*)take((size_t)768 * 256 * 2);
    bf16_t* W2b   = (bf16_t*)take((size_t)256 * 256 * 2);
    bf16_t* W3b   = (bf16_t*)take((size_t)256 * 256 * 2);
    bf16_t* attnb = (bf16_t*)take((size_t)8192 * 256 * 2);
    bf16_t* seqb  = (bf16_t*)take((size_t)8192 * 256 * 2);
    bf16_t* seqTb = (bf16_t*)take((size_t)256 * 8192 * 2);
    char*   regA  = (char*)take((size_t)8192 * 768 * 4);   // 25.2 MB shared region
    float*  qkv   = (float*)regA;                          // [8192,768], dies after MHA
    float*  seqf  = (float*)regA;                          // [8192,256], dies after cvt_seq
    bf16_t* aggb  = (bf16_t*)(regA + (size_t)8192 * 256 * 4); // [16384,256] bf16, after seqf

    // 1) bf16 casts of all MFMA operands
    k_cvt<<<2048, 256, 0, stream>>>(user_feat, Ub, 16384 * 256 / 4);
    k_cvt<<<2048, 256, 0, stream>>>(seq_feat, Xb, 8192 * 256 / 4);
    k_cvt<<<192, 256, 0, stream>>>(in_proj_w, W1b, 768 * 256 / 4);
    k_cvt<<<64, 256, 0, stream>>>(out_proj_w, W2b, 256 * 256 / 4);
    k_cvt<<<64, 256, 0, stream>>>(trans_w, W3b, 256 * 256 / 4);

    // 2) qkv = seq_feat @ in_proj_w^T + in_proj_b   [8192,768]
    k_gemm_bt<<<dim3(768 / 64, 8192 / 64), 256, 0, stream>>>(Xb, W1b, in_proj_b, nullptr, qkv, 768);

    // 3) MHA -> attn bf16 [8192,256]
    k_mha<<<1024, 128, 0, stream>>>(qkv, attnb);

    // 4) seq = attn @ out_proj_w^T + out_proj_b   [8192,256] f32
    k_gemm_bt<<<dim3(256 / 64, 8192 / 64), 256, 0, stream>>>(attnb, W2b, out_proj_b, nullptr, seqf, 256);

    // 5) seq -> bf16 (row-major + transposed)
    k_cvt_seq<<<dim3(4, 128), 256, 0, stream>>>(seqf, seqb, seqTb);

    // 6) fused user-attention -> agg bf16 [16384,256]
    k_user_attn<<<256, 512, 0, stream>>>(Ub, seqb, seqTb, aggb);

    // 7) out = user_feat + agg @ trans_w^T + trans_b
    k_gemm_bt<<<dim3(256 / 64, 16384 / 64), 256, 0, stream>>>(aggb, W3b, trans_b, user_feat, out, 256);
}

// Round 2
// 262.881 us; speedup vs baseline: 1.4655x; 1.4655x over previous
//
#include <hip/hip_runtime.h>

// ---------------------------------------------------------------------------
// RefineIUGraphLayer: D=256, H=16, HD=16, N=16384, B=64, S=128, M=8192
//   1) qkv = seq_feat @ in_proj_w^T + in_proj_b            (bf16 MFMA gemm)
//   2) attn = MHA(qkv)                                     (f32 per-thread)
//   3) seq = attn @ out_proj_w^T + out_proj_b              (bf16 MFMA gemm)
//   4) agg = p1norm(user @ seq^T) @ seq / M  (fused, j-split x2 + combine)
//   5) out = user + agg @ trans_w^T + trans_b              (bf16 MFMA gemm)
// ---------------------------------------------------------------------------

typedef __bf16 bf16_t;
typedef __bf16 bf16x8 __attribute__((ext_vector_type(8)));
typedef __bf16 bf16x4 __attribute__((ext_vector_type(4)));
typedef float  f32x4  __attribute__((ext_vector_type(4)));
typedef unsigned int u32x4 __attribute__((ext_vector_type(4)));

#define MFMA16(a, b, c) __builtin_amdgcn_mfma_f32_16x16x32_bf16((a), (b), (c), 0, 0, 0)

// 3-bit chunk XOR swizzles (write & read identically; involution).
__device__ __forceinline__ int swz256(int row, int k) { return row * 256 + (k ^ ((row & 7) << 3)); }
__device__ __forceinline__ int swz64 (int row, int k) { return row * 64  + (k ^ ((row & 7) << 3)); }
// P-tile byte swizzle: balanced for b16 writes (rows r,r+4,r+8,r+12) AND
// b128 reads (rows l15, k-quarter l4).
__device__ __forceinline__ int pswz(int row) { return ((row & 3) << 4) ^ (((row >> 2) & 3) << 5); }

// --------------------------- f32 -> bf16 convert ---------------------------
__global__ void k_cvt(const float* __restrict__ s, bf16_t* __restrict__ d, int n4) {
    int i  = blockIdx.x * blockDim.x + threadIdx.x;
    int st = gridDim.x * blockDim.x;
    for (; i < n4; i += st) {
        float4 v = ((const float4*)s)[i];
        bf16x4 o = { (bf16_t)v.x, (bf16_t)v.y, (bf16_t)v.z, (bf16_t)v.w };
        ((bf16x4*)d)[i] = o;
    }
}

// --------- seq f32 [8192,256] -> bf16 row-major + bf16 transposed ----------
__global__ void k_cvt_seq(const float* __restrict__ seq, bf16_t* __restrict__ sb,
                          bf16_t* __restrict__ sTb) {
    __shared__ bf16_t t[64][65];
    const int c0 = blockIdx.x * 64;   // d base
    const int r0 = blockIdx.y * 64;   // j base
    const int tid = threadIdx.x;
#pragma unroll
    for (int i = 0; i < 16; ++i) {
        int e = i * 256 + tid;
        int lr = e >> 6, lc = e & 63;
        float v = seq[(size_t)(r0 + lr) * 256 + c0 + lc];
        bf16_t b = (bf16_t)v;
        sb[(size_t)(r0 + lr) * 256 + c0 + lc] = b;
        t[lc][lr] = b;
    }
    __syncthreads();
#pragma unroll
    for (int i = 0; i < 16; ++i) {
        int e = i * 256 + tid;
        int lr = e >> 6, lc = e & 63;
        sTb[(size_t)(c0 + lr) * 8192 + r0 + lc] = t[lr][lc];
    }
}

// ------------------- generic C = A @ B^T + bias (+resid) -------------------
__global__ __launch_bounds__(256, 1)
void k_gemm_bt(const bf16_t* __restrict__ A, const bf16_t* __restrict__ B,
               const float* __restrict__ bias, const float* __restrict__ resid,
               float* __restrict__ C, int N) {
    __shared__ bf16_t Al[64 * 256];
    __shared__ bf16_t Bl[64 * 256];
    const int tid  = threadIdx.x;
    const int lane = tid & 63;
    const int w    = tid >> 6;
    const int l15  = lane & 15;
    const int l4   = lane >> 4;
    const int rb = blockIdx.y * 64, cb = blockIdx.x * 64;

    {
        const u32x4* sa = (const u32x4*)(A + (size_t)rb * 256);
        const u32x4* sb = (const u32x4*)(B + (size_t)cb * 256);
        u32x4* da = (u32x4*)Al;
        u32x4* db = (u32x4*)Bl;
#pragma unroll
        for (int i = 0; i < 8; ++i) {
            int ch  = i * 256 + tid;
            int row = ch >> 5, cp = ch & 31;
            int sch = (ch & ~31) | (cp ^ (row & 7));
            da[sch] = sa[ch];
            db[sch] = sb[ch];
        }
    }
    __syncthreads();

    f32x4 acc[4];
#pragma unroll
    for (int n = 0; n < 4; ++n) acc[n] = (f32x4){0.f, 0.f, 0.f, 0.f};

#pragma unroll
    for (int t = 0; t < 8; ++t) {
        int k = t * 32 + l4 * 8;
        bf16x8 af = *(const bf16x8*)(Al + swz256(16 * w + l15, k));
#pragma unroll
        for (int n = 0; n < 4; ++n) {
            bf16x8 bfr = *(const bf16x8*)(Bl + swz256(16 * n + l15, k));
            acc[n] = MFMA16(af, bfr, acc[n]);
        }
    }

#pragma unroll
    for (int n = 0; n < 4; ++n) {
        int col = cb + 16 * n + l15;
        float bv = bias ? bias[col] : 0.f;
#pragma unroll
        for (int r = 0; r < 4; ++r) {
            int row = rb + 16 * w + l4 * 4 + r;
            size_t idx = (size_t)row * N + col;
            float v = acc[n][r] + bv;
            if (resid) v += resid[idx];
            C[idx] = v;
        }
    }
}

// ------------------------------- MHA (f32) ---------------------------------
__global__ __launch_bounds__(128, 1)
void k_mha(const float* __restrict__ qkv, bf16_t* __restrict__ attn) {
    __shared__ float Kl[128][17];
    __shared__ float Vl[128][17];
    const int bh = blockIdx.x;
    const int b = bh >> 4, h = bh & 15;
    const int t = threadIdx.x;
    const size_t rowbase = (size_t)b * 128;

    const float* qrow = qkv + (rowbase + t) * 768 + h * 16;
    const float* krow = qkv + (rowbase + t) * 768 + 256 + h * 16;
    const float* vrow = qkv + (rowbase + t) * 768 + 512 + h * 16;
    float q[16];
#pragma unroll
    for (int d = 0; d < 16; ++d) q[d] = qrow[d];
#pragma unroll
    for (int d = 0; d < 16; ++d) { Kl[t][d] = krow[d]; Vl[t][d] = vrow[d]; }
    __syncthreads();

    float m = -1e30f;
    for (int j = 0; j < 128; ++j) {
        float s = 0.f;
#pragma unroll
        for (int d = 0; d < 16; ++d) s += q[d] * Kl[j][d];
        m = fmaxf(m, s * 0.25f);
    }
    float sum = 0.f;
    float o[16];
#pragma unroll
    for (int d = 0; d < 16; ++d) o[d] = 0.f;
    for (int j = 0; j < 128; ++j) {
        float s = 0.f;
#pragma unroll
        for (int d = 0; d < 16; ++d) s += q[d] * Kl[j][d];
        float e = __expf(s * 0.25f - m);
        sum += e;
#pragma unroll
        for (int d = 0; d < 16; ++d) o[d] += e * Vl[j][d];
    }
    float inv = 1.f / sum;
    bf16_t* out = attn + (rowbase + t) * 256 + h * 16;
#pragma unroll
    for (int d = 0; d < 16; ++d) out[d] = (bf16_t)(o[d] * inv);
}

// ------------------- fused user-attention (the hot loop) -------------------
// Block: 128 q-rows, one j-half (4096 j's, 64 iters of 64). 8 waves (4r x 2c),
// U fragments register-resident, O-partial (bf16) + rowsum-partial (f32) out.
__global__ __launch_bounds__(512, 2)
void k_user_attn(const bf16_t* __restrict__ Ub, const bf16_t* __restrict__ Sq,
                 const bf16_t* __restrict__ SqT, bf16_t* __restrict__ Opart,
                 float* __restrict__ rsp) {
    __shared__ bf16_t Kl[64 * 256];   // seq tile   [64 j][256 d]  32 KB
    __shared__ bf16_t Tl[256 * 64];   // seqT tile  [256 d][64 j]  32 KB
    __shared__ bf16_t Pl[128 * 64];   // scores     [128 q][64 j]  16 KB
    __shared__ float  rs[128];

    const int tid  = threadIdx.x;
    const int lane = tid & 63;
    const int wid  = tid >> 6;     // 0..7
    const int wr   = wid >> 1;     // 0..3 : 32-row q strip
    const int wc   = wid & 1;      // 0..1 : j/d column half
    const int l15  = lane & 15;
    const int l4   = lane >> 4;
    const int q0   = blockIdx.x * 128;
    const int jy   = blockIdx.y;   // 0..1
    const int jbase = jy * 4096;

    if (tid < 128) rs[tid] = 0.f;

    // U fragments in registers: rows q0 + 32*wr + 16*rt + l15, k = t*32 + l4*8
    bf16x8 uf[2][8];
#pragma unroll
    for (int rt = 0; rt < 2; ++rt) {
        const bf16_t* up = Ub + (size_t)(q0 + 32 * wr + 16 * rt + l15) * 256 + l4 * 8;
#pragma unroll
        for (int t = 0; t < 8; ++t) uf[rt][t] = *(const bf16x8*)(up + t * 32);
    }

    f32x4 oacc[2][8];
#pragma unroll
    for (int rt = 0; rt < 2; ++rt)
#pragma unroll
        for (int n = 0; n < 8; ++n) oacc[rt][n] = (f32x4){0.f, 0.f, 0.f, 0.f};
    float rsacc[2][4] = {{0.f, 0.f, 0.f, 0.f}, {0.f, 0.f, 0.f, 0.f}};

    u32x4 sreg[4], treg[4];
    auto load_tiles = [&](int j0) {
        const u32x4* src = (const u32x4*)(Sq + (size_t)j0 * 256);
#pragma unroll
        for (int i = 0; i < 4; ++i) sreg[i] = src[i * 512 + tid];
#pragma unroll
        for (int i = 0; i < 4; ++i) {
            int ch = i * 512 + tid;           // 0..2047
            int dr = ch >> 3, cp = ch & 7;    // d row, 16B chunk
            treg[i] = *(const u32x4*)(SqT + (size_t)dr * 8192 + j0 + cp * 8);
        }
    };
    load_tiles(jbase);

    char* Pb = (char*)Pl;
    for (int it = 0; it < 64; ++it) {
        __syncthreads();   // (a) prev iter's LDS reads complete
        {   // write staged tiles to LDS, swizzled
            u32x4* dk = (u32x4*)Kl;
            u32x4* dt = (u32x4*)Tl;
#pragma unroll
            for (int i = 0; i < 4; ++i) {
                int ch = i * 512 + tid;
                int row = ch >> 5, cp = ch & 31;
                dk[(ch & ~31) | (cp ^ (row & 7))] = sreg[i];
            }
#pragma unroll
            for (int i = 0; i < 4; ++i) {
                int ch = i * 512 + tid;
                int row = ch >> 3, cp = ch & 7;
                dt[(ch & ~7) | (cp ^ (row & 7))] = treg[i];
            }
        }
        __syncthreads();   // (b) tiles visible
        if (it + 1 < 64) load_tiles(jbase + (it + 1) * 64);  // prefetch under compute

        // ---- S-GEMM: S[128x32(wc)] = U(regs) @ K_tile^T, K=256 ----
        f32x4 sacc[2][2];
#pragma unroll
        for (int rt = 0; rt < 2; ++rt)
#pragma unroll
            for (int jt = 0; jt < 2; ++jt) sacc[rt][jt] = (f32x4){0.f, 0.f, 0.f, 0.f};
#pragma unroll
        for (int t = 0; t < 8; ++t) {
            int k = t * 32 + l4 * 8;
#pragma unroll
            for (int jt = 0; jt < 2; ++jt) {
                bf16x8 bfr = *(const bf16x8*)(Kl + swz256(32 * wc + 16 * jt + l15, k));
#pragma unroll
                for (int rt = 0; rt < 2; ++rt)
                    sacc[rt][jt] = MFMA16(uf[rt][t], bfr, sacc[rt][jt]);
            }
        }
        // ---- |.| row partial sums + P -> bf16 LDS (balanced swizzle) ----
#pragma unroll
        for (int rt = 0; rt < 2; ++rt)
#pragma unroll
            for (int jt = 0; jt < 2; ++jt)
#pragma unroll
                for (int r = 0; r < 4; ++r) {
                    float v = sacc[rt][jt][r];
                    rsacc[rt][r] += fabsf(v);
                    int prow = 32 * wr + 16 * rt + l4 * 4 + r;
                    int pcol = 32 * wc + 16 * jt + l15;
                    *(bf16_t*)(Pb + prow * 128 + ((pcol * 2) ^ pswz(prow))) = (bf16_t)v;
                }
        __syncthreads();   // (c) P visible

        // ---- PV: O[128x128(wc)] += P @ T_tile^T, K=64 ----
#pragma unroll
        for (int kt = 0; kt < 2; ++kt) {
            bf16x8 paf[2];
#pragma unroll
            for (int rt = 0; rt < 2; ++rt) {
                int prow = 32 * wr + 16 * rt + l15;
                paf[rt] = *(const bf16x8*)(Pb + prow * 128 + ((kt * 64 + l4 * 16) ^ pswz(prow)));
            }
#pragma unroll
            for (int n = 0; n < 8; ++n) {
                bf16x8 bfr = *(const bf16x8*)(Tl + swz64(128 * wc + 16 * n + l15, kt * 32 + l4 * 8));
#pragma unroll
                for (int rt = 0; rt < 2; ++rt)
                    oacc[rt][n] = MFMA16(paf[rt], bfr, oacc[rt][n]);
            }
        }
    }

    // ---- row-sum reduce: 16-lane butterfly then LDS atomic ----
#pragma unroll
    for (int rt = 0; rt < 2; ++rt)
#pragma unroll
        for (int r = 0; r < 4; ++r) {
            float v = rsacc[rt][r];
            v += __shfl_xor(v, 1, 16);
            v += __shfl_xor(v, 2, 16);
            v += __shfl_xor(v, 4, 16);
            v += __shfl_xor(v, 8, 16);
            if (l15 == 0) atomicAdd(&rs[32 * wr + 16 * rt + l4 * 4 + r], v);
        }
    __syncthreads();
    if (tid < 128) rsp[(size_t)jy * 16384 + q0 + tid] = rs[tid];

    bf16_t* ob = Opart + (size_t)jy * 16384 * 256;
#pragma unroll
    for (int rt = 0; rt < 2; ++rt)
#pragma unroll
        for (int r = 0; r < 4; ++r) {
            int row = q0 + 32 * wr + 16 * rt + l4 * 4 + r;
#pragma unroll
            for (int n = 0; n < 8; ++n)
                ob[(size_t)row * 256 + 128 * wc + 16 * n + l15] = (bf16_t)oacc[rt][n][r];
        }
}

// ---- combine j-halves: agg = (O0+O1) / (max(rs0+rs1,1e-12)*8192) ----------
__global__ void k_combine(const bf16_t* __restrict__ O, const float* __restrict__ rsp,
                          bf16_t* __restrict__ aggb) {
    int idx = blockIdx.x * blockDim.x + threadIdx.x;   // 16384*32 groups of 8
    int row = idx >> 5, g = idx & 31;
    float inv = 1.f / (fmaxf(rsp[row] + rsp[16384 + row], 1e-12f) * 8192.f);
    bf16x8 a = *(const bf16x8*)(O + (size_t)row * 256 + g * 8);
    bf16x8 b = *(const bf16x8*)(O + (size_t)16384 * 256 + (size_t)row * 256 + g * 8);
    bf16x8 o;
#pragma unroll
    for (int e = 0; e < 8; ++e) o[e] = (bf16_t)(((float)a[e] + (float)b[e]) * inv);
    *(bf16x8*)(aggb + (size_t)row * 256 + g * 8) = o;
}

// ---------------------------------------------------------------------------
extern "C" void kernel_launch(void* const* d_in, const int* in_sizes, int n_in,
                              void* d_out, int out_size, void* d_ws, size_t ws_size,
                              hipStream_t stream) {
    const float* user_feat  = (const float*)d_in[0];   // [16384,256]
    const float* seq_feat   = (const float*)d_in[1];   // [64,128,256]
    const float* in_proj_w  = (const float*)d_in[2];   // [768,256]
    const float* in_proj_b  = (const float*)d_in[3];   // [768]
    const float* out_proj_w = (const float*)d_in[4];   // [256,256]
    const float* out_proj_b = (const float*)d_in[5];   // [256]
    const float* trans_w    = (const float*)d_in[6];   // [256,256]
    const float* trans_b    = (const float*)d_in[7];   // [256]
    float* out = (float*)d_out;                        // [16384,256]

    char* w = (char*)d_ws;
    size_t off = 0;
    auto take = [&](size_t bytes) { void* p = w + off; off += (bytes + 255) & ~(size_t)255; return p; };
    bf16_t* Ub    = (bf16_t*)take((size_t)16384 * 256 * 2);
    bf16_t* Xb    = (bf16_t*)take((size_t)8192 * 256 * 2);   // dead after gemm1 -> rsp lives here
    bf16_t* W1b   = (bf16_t*)take((size_t)768 * 256 * 2);
    bf16_t* W2b   = (bf16_t*)take((size_t)256 * 256 * 2);
    bf16_t* W3b   = (bf16_t*)take((size_t)256 * 256 * 2);
    bf16_t* attnb = (bf16_t*)take((size_t)8192 * 256 * 2);
    bf16_t* seqb  = (bf16_t*)take((size_t)8192 * 256 * 2);
    bf16_t* seqTb = (bf16_t*)take((size_t)256 * 8192 * 2);
    char*   regA  = (char*)take((size_t)8192 * 768 * 4);     // 25.17 MB shared region
    float*  qkv   = (float*)regA;                            // [8192,768], dies after MHA
    float*  seqf  = (float*)regA;                            // [8192,256], dies after cvt_seq
    bf16_t* Opart = (bf16_t*)regA;                           // [2,16384,256] bf16 = 16.78 MB
    bf16_t* aggb  = (bf16_t*)(regA + (size_t)2 * 16384 * 256 * 2); // 8.39 MB (fits exactly)
    float*  rsp   = (float*)Xb;                              // [2,16384] f32 (Xb dead by then)

    // 1) bf16 casts of MFMA operands
    k_cvt<<<2048, 256, 0, stream>>>(user_feat, Ub, 16384 * 256 / 4);
    k_cvt<<<2048, 256, 0, stream>>>(seq_feat, Xb, 8192 * 256 / 4);
    k_cvt<<<192, 256, 0, stream>>>(in_proj_w, W1b, 768 * 256 / 4);
    k_cvt<<<64, 256, 0, stream>>>(out_proj_w, W2b, 256 * 256 / 4);
    k_cvt<<<64, 256, 0, stream>>>(trans_w, W3b, 256 * 256 / 4);

    // 2) qkv = seq_feat @ in_proj_w^T + in_proj_b   [8192,768]
    k_gemm_bt<<<dim3(768 / 64, 8192 / 64), 256, 0, stream>>>(Xb, W1b, in_proj_b, nullptr, qkv, 768);

    // 3) MHA -> attn bf16 [8192,256]
    k_mha<<<1024, 128, 0, stream>>>(qkv, attnb);

    // 4) seq = attn @ out_proj_w^T + out_proj_b   [8192,256] f32
    k_gemm_bt<<<dim3(256 / 64, 8192 / 64), 256, 0, stream>>>(attnb, W2b, out_proj_b, nullptr, seqf, 256);

    // 5) seq -> bf16 (row-major + transposed)
    k_cvt_seq<<<dim3(4, 128), 256, 0, stream>>>(seqf, seqb, seqTb);

    // 6) fused user-attention, j-split x2 -> partials
    k_user_attn<<<dim3(128, 2), 512, 0, stream>>>(Ub, seqb, seqTb, Opart, rsp);

    // 6b) combine partials -> agg bf16 [16384,256]
    k_combine<<<2048, 256, 0, stream>>>(Opart, rsp, aggb);

    // 7) out = user_feat + agg @ trans_w^T + trans_b
    k_gemm_bt<<<dim3(256 / 64, 16384 / 64), 256, 0, stream>>>(aggb, W3b, trans_b, user_feat, out, 256);
}